// Round 1
// baseline (660.684 us; speedup 1.0000x reference)
//
#include <hip/hip_runtime.h>
#include <math.h>

#define Bn 4
#define Nn 4096
#define Kn 16
#define Cn 128
#define HIDn 64

// ws layout (float offsets)
#define OFF_WQKVT 0            // 128*384
#define OFF_W2T   49152        // 64*128
#define OFF_WM1T  57344        // 128*512
#define OFF_WM2T  122880       // 512*128
#define OFF_QM    188416       // B*N*C = 2097152
#define OFF_KM    2285568
#define OFF_VM    4382720
#define OFF_KV    6479872      // B*K*C*C = 1048576
#define OFF_AGG   7528448      // 2097152
#define OFF_FLAG  9625600      // 1 int

// ---------------- K0: weight transposes + idx dtype probe ----------------
__global__ void k0_prep(const float* __restrict__ Wqkv, const float* __restrict__ W2,
                        const float* __restrict__ Wm1, const float* __restrict__ Wm2,
                        const int* __restrict__ idx_raw, float* ws) {
  if (blockIdx.x == 0 && threadIdx.x == 0) {
    int any = 0;
    for (int i = 0; i < 64; ++i) any |= idx_raw[2 * i + 1];
    ((int*)(ws + OFF_FLAG))[0] = (any == 0) ? 1 : 0;   // 1 => idx is int64
  }
  int t = blockIdx.x * 256 + threadIdx.x;
  if (t < 49152) { int m = t / 128, c = t % 128; ws[OFF_WQKVT + c * 384 + m] = Wqkv[t]; return; }
  t -= 49152;
  if (t < 8192) { int c = t / 64, o = t % 64; ws[OFF_W2T + o * 128 + c] = W2[t]; return; }
  t -= 8192;
  if (t < 65536) { int h = t / 128, c = t % 128; ws[OFF_WM1T + c * 512 + h] = Wm1[t]; return; }
  t -= 65536;
  if (t < 65536) { int co = t / 512, h = t % 512; ws[OFF_WM2T + h * 128 + co] = Wm2[t]; return; }
}

// ---------------- K1: qkv = xt @ Wqkv^T -> Qm/Km/Vm [B,N,128] ----------------
__global__ __launch_bounds__(256) void k1_qkv(const float* __restrict__ x, float* ws) {
  __shared__ float xt[128 * 64];
  const float* WqkvT = ws + OFF_WQKVT;
  int b = blockIdx.x >> 6;
  int n0 = (blockIdx.x & 63) << 6;
  int t = threadIdx.x;
#pragma unroll
  for (int i = 0; i < 32; ++i) {
    int id = t + 256 * i;
    int c = id >> 6, j = id & 63;
    xt[(c << 6) + j] = x[(b * Cn + c) * Nn + n0 + j];
  }
  __syncthreads();
  int tn = t >> 4, td = t & 15;
  for (int mc = 0; mc < 384; mc += 128) {
    float acc[4][8];
#pragma unroll
    for (int ii = 0; ii < 4; ++ii)
#pragma unroll
      for (int jj = 0; jj < 8; ++jj) acc[ii][jj] = 0.f;
#pragma unroll 4
    for (int c = 0; c < 128; ++c) {
      float q[4];
#pragma unroll
      for (int ii = 0; ii < 4; ++ii) q[ii] = xt[(c << 6) + tn + (ii << 4)];
      const float* wp = &WqkvT[c * 384 + mc + td * 8];
      float4 w0 = *(const float4*)wp;
      float4 w1 = *(const float4*)(wp + 4);
      float w[8] = {w0.x, w0.y, w0.z, w0.w, w1.x, w1.y, w1.z, w1.w};
#pragma unroll
      for (int ii = 0; ii < 4; ++ii)
#pragma unroll
        for (int jj = 0; jj < 8; ++jj) acc[ii][jj] = fmaf(q[ii], w[jj], acc[ii][jj]);
    }
    float* dst = ws + (mc == 0 ? OFF_QM : (mc == 128 ? OFF_KM : OFF_VM));
#pragma unroll
    for (int ii = 0; ii < 4; ++ii) {
      int n = n0 + tn + (ii << 4);
      float4 o0 = {acc[ii][0], acc[ii][1], acc[ii][2], acc[ii][3]};
      float4 o1 = {acc[ii][4], acc[ii][5], acc[ii][6], acc[ii][7]};
      *(float4*)&dst[(b * Nn + n) * Cn + td * 8] = o0;
      *(float4*)&dst[(b * Nn + n) * Cn + td * 8 + 4] = o1;
    }
  }
}

// ---------------- K2: kv[b,k,c,d] = sum_n Knorm * Vrel ----------------
#define CH2 8
__global__ __launch_bounds__(256, 2) void k2_kv(const float* __restrict__ pos,
                                                const float* __restrict__ dist,
                                                const int* __restrict__ idxp,
                                                const float* __restrict__ W1,
                                                const float* __restrict__ b1,
                                                const float* __restrict__ b2,
                                                float* ws) {
  __shared__ float W2Ts[64 * 128];
  __shared__ float W1s[640];
  __shared__ float b1s[64];
  __shared__ float b2s[128];
  __shared__ float h_t[64 * 33];     // [o][g], padded
  __shared__ float k_lds[32 * 128];
  __shared__ float v_lds[32 * 128];
  __shared__ int jn_s[32];

  const float* Km = ws + OFF_KM;
  const float* Vm = ws + OFF_VM;
  const float* W2T = ws + OFF_W2T;
  float* kv = ws + OFF_KV;
  int flag = ((const int*)(ws + OFF_FLAG))[0];

  int bid = blockIdx.x;
  int ch = bid & (CH2 - 1);
  int bk = bid / CH2;
  int k = bk & 15, b = bk >> 4;
  int t = threadIdx.x;

#pragma unroll
  for (int i = 0; i < 32; ++i) W2Ts[t + 256 * i] = W2T[t + 256 * i];
  for (int i = t; i < 640; i += 256) W1s[i] = W1[i];
  if (t < 64) b1s[t] = b1[t];
  if (t < 128) b2s[t] = b2[t];

  float acc[8][8];
#pragma unroll
  for (int i = 0; i < 8; ++i)
#pragma unroll
    for (int j = 0; j < 8; ++j) acc[i][j] = 0.f;

  int rg = t >> 4, cg = t & 15;     // phase C: r = rg*8+i, c2 = cg+16*j
  int tn2 = t >> 5, td = t & 31;    // phase B
  int g = t >> 3, l8 = t & 7;       // phase A

  int nbase = ch * (Nn / CH2);
  for (int it = 0; it < (Nn / CH2) / 32; ++it) {
    int n0 = nbase + it * 32;
    __syncthreads();
    // ---- Phase A: MLP layer 1 (per n: 8 lanes x 8 outputs) ----
    {
      int n = n0 + g;
      int fidx = (b * Nn + n) * Kn + k;
      int jn = flag ? idxp[2 * fidx] : idxp[fidx];
      float dd = dist[fidx];
      float pc0 = pos[(b * Nn + n) * 3 + 0], pc1 = pos[(b * Nn + n) * 3 + 1], pc2 = pos[(b * Nn + n) * 3 + 2];
      float pn0 = pos[(b * Nn + jn) * 3 + 0], pn1 = pos[(b * Nn + jn) * 3 + 1], pn2 = pos[(b * Nn + jn) * 3 + 2];
      float f10[10] = {pc0, pc1, pc2, pn0, pn1, pn2, pc0 - pn0, pc1 - pn1, pc2 - pn2, dd};
      if (l8 == 0) jn_s[g] = jn;
#pragma unroll
      for (int oo = 0; oo < 8; ++oo) {
        int o = l8 * 8 + oo;
        float a = b1s[o];
#pragma unroll
        for (int i2 = 0; i2 < 10; ++i2) a = fmaf(W1s[o * 10 + i2], f10[i2], a);
        h_t[o * 33 + g] = fmaxf(a, 0.f);
      }
    }
    __syncthreads();
    // ---- Phase B: pe = h^T @ W2T + b2; gather K/V; normalize ----
    {
      float pe[4][4];
#pragma unroll
      for (int ii = 0; ii < 4; ++ii)
#pragma unroll
        for (int j2 = 0; j2 < 4; ++j2) pe[ii][j2] = b2s[j2 * 32 + td];
#pragma unroll 4
      for (int o = 0; o < 64; ++o) {
        float hv[4];
#pragma unroll
        for (int ii = 0; ii < 4; ++ii) hv[ii] = h_t[o * 33 + tn2 * 4 + ii];
        float wv[4];
#pragma unroll
        for (int j2 = 0; j2 < 4; ++j2) wv[j2] = W2Ts[o * 128 + j2 * 32 + td];
#pragma unroll
        for (int ii = 0; ii < 4; ++ii)
#pragma unroll
          for (int j2 = 0; j2 < 4; ++j2) pe[ii][j2] = fmaf(hv[ii], wv[j2], pe[ii][j2]);
      }
#pragma unroll
      for (int ii = 0; ii < 4; ++ii) {
        int nn = tn2 * 4 + ii;
        int jn = jn_s[nn];
        const float* krow = &Km[(b * Nn + jn) * Cn];
        const float* vrow = &Vm[(b * Nn + jn) * Cn];
        float kr[4], vr[4];
        float ss = 0.f;
#pragma unroll
        for (int j2 = 0; j2 < 4; ++j2) {
          float kg = krow[j2 * 32 + td];
          float vg = vrow[j2 * 32 + td];
          kr[j2] = kg + pe[ii][j2];
          vr[j2] = fmaxf(vg + pe[ii][j2], 0.f);
          ss = fmaf(kr[j2], kr[j2], ss);
        }
#pragma unroll
        for (int m = 16; m >= 1; m >>= 1) ss += __shfl_xor(ss, m);
        float sc = 1.f / fmaxf(sqrtf(ss), 1e-12f);
#pragma unroll
        for (int j2 = 0; j2 < 4; ++j2) {
          k_lds[nn * 128 + j2 * 32 + td] = kr[j2] * sc;
          v_lds[nn * 128 + j2 * 32 + td] = vr[j2];
        }
      }
    }
    __syncthreads();
    // ---- Phase C: 128x128 rank-1 updates ----
#pragma unroll 4
    for (int nn = 0; nn < 32; ++nn) {
      float4 ka = *(const float4*)&k_lds[nn * 128 + rg * 8];
      float4 kb = *(const float4*)&k_lds[nn * 128 + rg * 8 + 4];
      float kk[8] = {ka.x, ka.y, ka.z, ka.w, kb.x, kb.y, kb.z, kb.w};
      float vv[8];
#pragma unroll
      for (int j = 0; j < 8; ++j) vv[j] = v_lds[nn * 128 + cg + 16 * j];
#pragma unroll
      for (int i = 0; i < 8; ++i)
#pragma unroll
        for (int j = 0; j < 8; ++j) acc[i][j] = fmaf(kk[i], vv[j], acc[i][j]);
    }
  }
  float* kvp = kv + (b * Kn + k) * Cn * Cn;
#pragma unroll
  for (int i = 0; i < 8; ++i) {
    int r = rg * 8 + i;
#pragma unroll
    for (int j = 0; j < 8; ++j) atomicAdd(&kvp[r * Cn + cg + 16 * j], acc[i][j]);
  }
}

// ---------------- K3: agg[b,n,d] = (1/N) sum_k Qn . kv ----------------
__global__ __launch_bounds__(256, 2) void k3_agg(const int* __restrict__ idxp, float* ws) {
  __shared__ float qn[32 * 130];
  const float* Qm = ws + OFF_QM;
  const float* kvg = ws + OFF_KV;
  float* agg = ws + OFF_AGG;
  int flag = ((const int*)(ws + OFF_FLAG))[0];
  int b = blockIdx.x >> 7;
  int n0 = (blockIdx.x & 127) << 5;
  int t = threadIdx.x;
  int g = t >> 3, l8 = t & 7;   // staging
  int tn = t >> 4, td = t & 15; // compute: n = tn+16*ii, d = td*8+jj
  float acc[2][8];
#pragma unroll
  for (int ii = 0; ii < 2; ++ii)
#pragma unroll
    for (int jj = 0; jj < 8; ++jj) acc[ii][jj] = 0.f;
  for (int k = 0; k < 16; ++k) {
    __syncthreads();
    {
      int n = n0 + g;
      int fidx = (b * Nn + n) * Kn + k;
      int jn = flag ? idxp[2 * fidx] : idxp[fidx];
      const float* qrow = &Qm[(b * Nn + jn) * Cn];
      float vv[16];
      float ss = 0.f;
#pragma unroll
      for (int cc = 0; cc < 16; ++cc) { vv[cc] = qrow[l8 + 8 * cc]; ss = fmaf(vv[cc], vv[cc], ss); }
      ss += __shfl_xor(ss, 1); ss += __shfl_xor(ss, 2); ss += __shfl_xor(ss, 4);
      float sc = 1.f / fmaxf(sqrtf(ss), 1e-12f);
#pragma unroll
      for (int cc = 0; cc < 16; ++cc) qn[g * 130 + l8 + 8 * cc] = vv[cc] * sc;
    }
    __syncthreads();
    const float* kvp = &kvg[(b * Kn + k) * Cn * Cn];
#pragma unroll 4
    for (int c = 0; c < 128; ++c) {
      float q0 = qn[tn * 130 + c];
      float q1 = qn[(tn + 16) * 130 + c];
      const float* wp = &kvp[c * Cn + td * 8];
      float4 w0 = *(const float4*)wp;
      float4 w1 = *(const float4*)(wp + 4);
      float w[8] = {w0.x, w0.y, w0.z, w0.w, w1.x, w1.y, w1.z, w1.w};
#pragma unroll
      for (int jj = 0; jj < 8; ++jj) {
        acc[0][jj] = fmaf(q0, w[jj], acc[0][jj]);
        acc[1][jj] = fmaf(q1, w[jj], acc[1][jj]);
      }
    }
  }
  const float inv = 1.f / (float)Nn;
#pragma unroll
  for (int ii = 0; ii < 2; ++ii) {
    int n = n0 + tn + 16 * ii;
    float4 o0 = {acc[ii][0] * inv, acc[ii][1] * inv, acc[ii][2] * inv, acc[ii][3] * inv};
    float4 o1 = {acc[ii][4] * inv, acc[ii][5] * inv, acc[ii][6] * inv, acc[ii][7] * inv};
    *(float4*)&agg[(b * Nn + n) * Cn + td * 8] = o0;
    *(float4*)&agg[(b * Nn + n) * Cn + td * 8 + 4] = o1;
  }
}

// ---------------- K4: out = relu(agg@Wm1^T+bm1)@Wm2^T + bm2 + xt ----------------
__global__ __launch_bounds__(256, 2) void k4_mlp(const float* __restrict__ x,
                                                 const float* __restrict__ bm1,
                                                 const float* __restrict__ bm2,
                                                 float* __restrict__ out, float* ws) {
  __shared__ float a_s[32 * 132];
  __shared__ float h_s[32 * 132];   // reused as out_s[128*33]
  const float* agg = ws + OFF_AGG;
  const float* Wm1T = ws + OFF_WM1T;
  const float* Wm2T = ws + OFF_WM2T;
  int b = blockIdx.x >> 7;
  int n0 = (blockIdx.x & 127) << 5;
  int t = threadIdx.x;
  int tn = t >> 4, td = t & 15;   // n = tn+16*ii (ii 0..1), h/co = td*8+jj
#pragma unroll
  for (int i = 0; i < 4; ++i) {
    int f4 = t + 256 * i;
    int row = f4 >> 5, c4 = f4 & 31;
    float4 v = *(const float4*)&agg[(b * Nn + n0 + row) * Cn + c4 * 4];
    *(float4*)&a_s[row * 132 + c4 * 4] = v;
  }
  __syncthreads();
  float oacc[2][8];
#pragma unroll
  for (int ii = 0; ii < 2; ++ii)
#pragma unroll
    for (int jj = 0; jj < 8; ++jj) oacc[ii][jj] = bm2[td * 8 + jj];
  for (int hc = 0; hc < 512; hc += 128) {
    float hacc[2][8];
#pragma unroll
    for (int ii = 0; ii < 2; ++ii)
#pragma unroll
      for (int jj = 0; jj < 8; ++jj) hacc[ii][jj] = bm1[hc + td * 8 + jj];
#pragma unroll 4
    for (int c = 0; c < 128; ++c) {
      float a0 = a_s[tn * 132 + c];
      float a1 = a_s[(tn + 16) * 132 + c];
      const float* wp = &Wm1T[c * 512 + hc + td * 8];
      float4 w0 = *(const float4*)wp;
      float4 w1 = *(const float4*)(wp + 4);
      float w[8] = {w0.x, w0.y, w0.z, w0.w, w1.x, w1.y, w1.z, w1.w};
#pragma unroll
      for (int jj = 0; jj < 8; ++jj) {
        hacc[0][jj] = fmaf(a0, w[jj], hacc[0][jj]);
        hacc[1][jj] = fmaf(a1, w[jj], hacc[1][jj]);
      }
    }
    __syncthreads();
#pragma unroll
    for (int ii = 0; ii < 2; ++ii) {
      float4 hw0 = {fmaxf(hacc[ii][0], 0.f), fmaxf(hacc[ii][1], 0.f), fmaxf(hacc[ii][2], 0.f), fmaxf(hacc[ii][3], 0.f)};
      float4 hw1 = {fmaxf(hacc[ii][4], 0.f), fmaxf(hacc[ii][5], 0.f), fmaxf(hacc[ii][6], 0.f), fmaxf(hacc[ii][7], 0.f)};
      *(float4*)&h_s[(tn + 16 * ii) * 132 + td * 8] = hw0;
      *(float4*)&h_s[(tn + 16 * ii) * 132 + td * 8 + 4] = hw1;
    }
    __syncthreads();
#pragma unroll 4
    for (int hh = 0; hh < 128; ++hh) {
      float h0 = h_s[tn * 132 + hh];
      float h1 = h_s[(tn + 16) * 132 + hh];
      const float* wp2 = &Wm2T[(hc + hh) * 128 + td * 8];
      float4 w0 = *(const float4*)wp2;
      float4 w1 = *(const float4*)(wp2 + 4);
      float w[8] = {w0.x, w0.y, w0.z, w0.w, w1.x, w1.y, w1.z, w1.w};
#pragma unroll
      for (int jj = 0; jj < 8; ++jj) {
        oacc[0][jj] = fmaf(h0, w[jj], oacc[0][jj]);
        oacc[1][jj] = fmaf(h1, w[jj], oacc[1][jj]);
      }
    }
    __syncthreads();   // protect h_s before next chunk's writes
  }
  float* out_s = h_s;  // 128*33 = 4224 floats fits
#pragma unroll
  for (int ii = 0; ii < 2; ++ii)
#pragma unroll
    for (int jj = 0; jj < 8; ++jj) out_s[(td * 8 + jj) * 33 + tn + 16 * ii] = oacc[ii][jj];
  __syncthreads();
#pragma unroll
  for (int i = 0; i < 16; ++i) {
    int id = t + 256 * i;
    int co = id >> 5, j = id & 31;
    out[(b * Cn + co) * Nn + n0 + j] = out_s[co * 33 + j] + x[(b * Cn + co) * Nn + n0 + j];
  }
}

extern "C" void kernel_launch(void* const* d_in, const int* in_sizes, int n_in,
                              void* d_out, int out_size, void* d_ws, size_t ws_size,
                              hipStream_t stream) {
  const float* pos  = (const float*)d_in[0];
  const float* x    = (const float*)d_in[1];
  const int*   idx  = (const int*)d_in[2];
  const float* dist = (const float*)d_in[3];
  const float* Wqkv = (const float*)d_in[4];
  const float* W1   = (const float*)d_in[5];
  const float* b1   = (const float*)d_in[6];
  const float* W2   = (const float*)d_in[7];
  const float* b2   = (const float*)d_in[8];
  const float* Wm1  = (const float*)d_in[9];
  const float* bm1  = (const float*)d_in[10];
  const float* Wm2  = (const float*)d_in[11];
  const float* bm2  = (const float*)d_in[12];
  float* out = (float*)d_out;
  float* ws = (float*)d_ws;

  hipMemsetAsync(ws + OFF_KV, 0, (size_t)Bn * Kn * Cn * Cn * sizeof(float), stream);
  hipLaunchKernelGGL(k0_prep, dim3(736), dim3(256), 0, stream, Wqkv, W2, Wm1, Wm2, idx, ws);
  hipLaunchKernelGGL(k1_qkv, dim3(Bn * 64), dim3(256), 0, stream, x, ws);
  hipLaunchKernelGGL(k2_kv, dim3(Bn * Kn * CH2), dim3(256), 0, stream, pos, dist, idx, W1, b1, b2, ws);
  hipLaunchKernelGGL(k3_agg, dim3(Bn * 128), dim3(256), 0, stream, idx, ws);
  hipLaunchKernelGGL(k4_mlp, dim3(Bn * 128), dim3(256), 0, stream, x, bm1, bm2, out, ws);
}

// Round 2
// 326.689 us; speedup vs baseline: 2.0224x; 2.0224x over previous
//
#include <hip/hip_runtime.h>
#include <math.h>

#define Bn 4
#define Nn 4096
#define Kn 16
#define Cn 128
#define HIDn 64

// ws layout (float offsets)
#define OFF_WQKVT 0            // 128*384
#define OFF_WM1T  49152       // 128*512
#define OFF_WM2T  114688      // 512*128
#define OFF_QNBF  180224      // B*N*C bf16 = 1048576 floats
#define OFF_KM    1228800     // B*N*C f32
#define OFF_VM    3325952     // B*N*C f32 (later aliased as AGG1)
#define OFF_KVT32 5423104     // B*K*C*C f32 (atomic target, kvT layout [b,k,d,c])
#define OFF_KVTBF 6471680     // B*K*C*C bf16 = 524288 floats
#define OFF_AGG0  6995968     // B*N*C f32
#define OFF_FLAG  9093120     // 1 int

typedef short bf16x8 __attribute__((ext_vector_type(8)));
typedef float f32x4 __attribute__((ext_vector_type(4)));

__device__ inline unsigned short f2bf(float f) {
  union { float f; unsigned u; } v; v.f = f;
  unsigned r = v.u + 0x7fffu + ((v.u >> 16) & 1u);
  return (unsigned short)(r >> 16);
}

// ---------------- K0: weight transposes + idx dtype probe ----------------
__global__ void k0_prep(const float* __restrict__ Wqkv,
                        const float* __restrict__ Wm1, const float* __restrict__ Wm2,
                        const int* __restrict__ idx_raw, float* ws) {
  if (blockIdx.x == 0 && threadIdx.x == 0) {
    int any = 0;
    for (int i = 0; i < 64; ++i) any |= idx_raw[2 * i + 1];
    ((int*)(ws + OFF_FLAG))[0] = (any == 0) ? 1 : 0;   // 1 => idx is int64
  }
  int t = blockIdx.x * 256 + threadIdx.x;
  if (t < 49152) { int m = t / 128, c = t % 128; ws[OFF_WQKVT + c * 384 + m] = Wqkv[t]; return; }
  t -= 49152;
  if (t < 65536) { int h = t / 128, c = t % 128; ws[OFF_WM1T + c * 512 + h] = Wm1[t]; return; }
  t -= 65536;
  if (t < 65536) { int co = t / 512, h = t % 512; ws[OFF_WM2T + h * 128 + co] = Wm2[t]; return; }
}

// ---------------- K1: qkv GEMM; Q -> normalized bf16, K/V -> f32 ----------------
__global__ __launch_bounds__(256) void k1_qkv(const float* __restrict__ x, float* ws) {
  __shared__ float xt[128 * 64];
  const float* WqkvT = ws + OFF_WQKVT;
  unsigned short* Qnbf = (unsigned short*)(ws + OFF_QNBF);
  int b = blockIdx.x >> 6;
  int n0 = (blockIdx.x & 63) << 6;
  int t = threadIdx.x;
#pragma unroll
  for (int i = 0; i < 32; ++i) {
    int id = t + 256 * i;
    int c = id >> 6, j = id & 63;
    xt[(c << 6) + j] = x[(b * Cn + c) * Nn + n0 + j];
  }
  __syncthreads();
  int tn = t >> 4, td = t & 15;
  for (int mc = 0; mc < 384; mc += 128) {
    float acc[4][8];
#pragma unroll
    for (int ii = 0; ii < 4; ++ii)
#pragma unroll
      for (int jj = 0; jj < 8; ++jj) acc[ii][jj] = 0.f;
#pragma unroll 4
    for (int c = 0; c < 128; ++c) {
      float q[4];
#pragma unroll
      for (int ii = 0; ii < 4; ++ii) q[ii] = xt[(c << 6) + tn + (ii << 4)];
      const float* wp = &WqkvT[c * 384 + mc + td * 8];
      float4 w0 = *(const float4*)wp;
      float4 w1 = *(const float4*)(wp + 4);
      float w[8] = {w0.x, w0.y, w0.z, w0.w, w1.x, w1.y, w1.z, w1.w};
#pragma unroll
      for (int ii = 0; ii < 4; ++ii)
#pragma unroll
        for (int jj = 0; jj < 8; ++jj) acc[ii][jj] = fmaf(q[ii], w[jj], acc[ii][jj]);
    }
    if (mc == 0) {
      // normalized Q in bf16
#pragma unroll
      for (int ii = 0; ii < 4; ++ii) {
        int n = n0 + tn + (ii << 4);
        float ss = 0.f;
#pragma unroll
        for (int jj = 0; jj < 8; ++jj) ss = fmaf(acc[ii][jj], acc[ii][jj], ss);
        ss += __shfl_xor(ss, 1); ss += __shfl_xor(ss, 2);
        ss += __shfl_xor(ss, 4); ss += __shfl_xor(ss, 8);
        float sc = 1.f / fmaxf(sqrtf(ss), 1e-12f);
        union { unsigned short us[8]; uint4 u4; } qv;
#pragma unroll
        for (int jj = 0; jj < 8; ++jj) qv.us[jj] = f2bf(acc[ii][jj] * sc);
        *(uint4*)&Qnbf[(b * Nn + n) * Cn + td * 8] = qv.u4;
      }
    } else {
      float* dst = ws + (mc == 128 ? OFF_KM : OFF_VM);
#pragma unroll
      for (int ii = 0; ii < 4; ++ii) {
        int n = n0 + tn + (ii << 4);
        float4 o0 = {acc[ii][0], acc[ii][1], acc[ii][2], acc[ii][3]};
        float4 o1 = {acc[ii][4], acc[ii][5], acc[ii][6], acc[ii][7]};
        *(float4*)&dst[(b * Nn + n) * Cn + td * 8] = o0;
        *(float4*)&dst[(b * Nn + n) * Cn + td * 8 + 4] = o1;
      }
    }
  }
}

// ---------------- K2: kvT[b,k,d,c] += sum_n Vrel[n,d]*Knorm[n,c]  (MFMA) ----------------
#define CH2 8
__global__ __launch_bounds__(256, 2) void k2_kv(const float* __restrict__ pos,
                                                const float* __restrict__ dist,
                                                const int* __restrict__ idxp,
                                                const float* __restrict__ W1,
                                                const float* __restrict__ b1,
                                                const float* __restrict__ W2,
                                                const float* __restrict__ b2,
                                                float* ws) {
  __shared__ __align__(16) unsigned short W2bf[128 * 72];  // [c][h], stride 72
  __shared__ __align__(16) unsigned short h_lds[32 * 72];  // [n][h], stride 72
  __shared__ float pe_lds[32 * 132];                        // [n][c]
  __shared__ __align__(16) unsigned short KnT[128 * 40];   // [c][n], stride 40
  __shared__ __align__(16) unsigned short VrT[128 * 40];   // [d][n], stride 40
  __shared__ float W1s[640];
  __shared__ float b1s[64];
  __shared__ float b2s[128];
  __shared__ int jn_s[32];

  const float* Km = ws + OFF_KM;
  const float* Vm = ws + OFF_VM;
  float* kvt = ws + OFF_KVT32;
  int flag = ((const int*)(ws + OFF_FLAG))[0];

  int bid = blockIdx.x;
  int ch = bid & (CH2 - 1);
  int bk = bid / CH2;
  int k = bk & 15, b = bk >> 4;
  int t = threadIdx.x;
  int w = t >> 6, l = t & 63;
  int ml = l & 15, gq = l >> 4;

  // stage weights
#pragma unroll
  for (int i = 0; i < 32; ++i) {
    int id = t + 256 * i;
    int c = id >> 6, h = id & 63;
    W2bf[c * 72 + h] = f2bf(W2[c * 64 + h]);
  }
  for (int i = t; i < 640; i += 256) W1s[i] = W1[i];
  if (t < 64) b1s[t] = b1[t];
  if (t < 128) b2s[t] = b2[t];

  f32x4 acc[2][8];
#pragma unroll
  for (int i = 0; i < 2; ++i)
#pragma unroll
    for (int j = 0; j < 8; ++j) acc[i][j] = (f32x4)0.f;

  int g = t >> 3, l8 = t & 7;      // phase A
  int tn2 = t >> 5, td = t & 31;   // phase B2

  for (int it = 0; it < 16; ++it) {
    int n0 = ch * 512 + it * 32;
    __syncthreads();
    // ---- Phase A: feat10 + MLP layer1 -> h_lds bf16 ----
    {
      int n = n0 + g;
      int fidx = (b * Nn + n) * Kn + k;
      int jn = flag ? idxp[2 * fidx] : idxp[fidx];
      if (l8 == 0) jn_s[g] = jn;
      float dd = dist[fidx];
      float pc0 = pos[(b * Nn + n) * 3 + 0], pc1 = pos[(b * Nn + n) * 3 + 1], pc2 = pos[(b * Nn + n) * 3 + 2];
      float pn0 = pos[(b * Nn + jn) * 3 + 0], pn1 = pos[(b * Nn + jn) * 3 + 1], pn2 = pos[(b * Nn + jn) * 3 + 2];
      float f10[10] = {pc0, pc1, pc2, pn0, pn1, pn2, pc0 - pn0, pc1 - pn1, pc2 - pn2, dd};
      union { unsigned short us[8]; uint4 u4; } hv;
#pragma unroll
      for (int oo = 0; oo < 8; ++oo) {
        int o = l8 * 8 + oo;
        float a = b1s[o];
#pragma unroll
        for (int i2 = 0; i2 < 10; ++i2) a = fmaf(W1s[o * 10 + i2], f10[i2], a);
        hv.us[oo] = f2bf(fmaxf(a, 0.f));
      }
      *(uint4*)&h_lds[g * 72 + l8 * 8] = hv.u4;
    }
    __syncthreads();
    // ---- Phase B1 (MFMA): pe[n][c] = h @ W2^T  (wave w: c in [32w,32w+32)) ----
    {
      f32x4 pacc[2][2];
#pragma unroll
      for (int i = 0; i < 2; ++i)
#pragma unroll
        for (int j = 0; j < 2; ++j) pacc[i][j] = (f32x4)0.f;
#pragma unroll
      for (int hc = 0; hc < 64; hc += 32) {
        bf16x8 av[2];
#pragma unroll
        for (int mf = 0; mf < 2; ++mf)
          av[mf] = *(const bf16x8*)&h_lds[(ml + 16 * mf) * 72 + hc + 8 * gq];
#pragma unroll
        for (int nf = 0; nf < 2; ++nf) {
          int c = 32 * w + 16 * nf + ml;
          bf16x8 bv = *(const bf16x8*)&W2bf[c * 72 + hc + 8 * gq];
          pacc[0][nf] = __builtin_amdgcn_mfma_f32_16x16x32_bf16(av[0], bv, pacc[0][nf], 0, 0, 0);
          pacc[1][nf] = __builtin_amdgcn_mfma_f32_16x16x32_bf16(av[1], bv, pacc[1][nf], 0, 0, 0);
        }
      }
#pragma unroll
      for (int mf = 0; mf < 2; ++mf)
#pragma unroll
        for (int nf = 0; nf < 2; ++nf) {
          int c = 32 * w + 16 * nf + ml;
          float b2v = b2s[c];
#pragma unroll
          for (int r = 0; r < 4; ++r)
            pe_lds[(16 * mf + 4 * gq + r) * 132 + c] = pacc[mf][nf][r] + b2v;
        }
    }
    __syncthreads();
    // ---- Phase B2: gather K/V + pe, normalize, write transposed bf16 tiles ----
    {
      unsigned short kout[4][4], vout[4][4];  // [q][ii]
#pragma unroll
      for (int ii = 0; ii < 4; ++ii) {
        int nn = tn2 * 4 + ii;
        int jn = jn_s[nn];
        const float* krow = &Km[(b * Nn + jn) * Cn];
        const float* vrow = &Vm[(b * Nn + jn) * Cn];
        float kr[4], vr[4];
        float ss = 0.f;
#pragma unroll
        for (int q = 0; q < 4; ++q) {
          int c = 32 * q + td;
          float pe = pe_lds[nn * 132 + c];
          kr[q] = krow[c] + pe;
          vr[q] = fmaxf(vrow[c] + pe, 0.f);
          ss = fmaf(kr[q], kr[q], ss);
        }
        ss += __shfl_xor(ss, 1); ss += __shfl_xor(ss, 2); ss += __shfl_xor(ss, 4);
        ss += __shfl_xor(ss, 8); ss += __shfl_xor(ss, 16);
        float sc = 1.f / fmaxf(sqrtf(ss), 1e-12f);
#pragma unroll
        for (int q = 0; q < 4; ++q) {
          kout[q][ii] = f2bf(kr[q] * sc);
          vout[q][ii] = f2bf(vr[q]);
        }
      }
#pragma unroll
      for (int q = 0; q < 4; ++q) {
        int c = 32 * q + td;
        union { unsigned short us[4]; uint2 u2; } ku, vu;
#pragma unroll
        for (int ii = 0; ii < 4; ++ii) { ku.us[ii] = kout[q][ii]; vu.us[ii] = vout[q][ii]; }
        *(uint2*)&KnT[c * 40 + tn2 * 4] = ku.u2;
        *(uint2*)&VrT[c * 40 + tn2 * 4] = vu.u2;
      }
    }
    __syncthreads();
    // ---- Phase C (MFMA): kvT[d][c] += VrT[d][:] * KnT[c][:]  (wave w: d in [32w,32w+32)) ----
    {
      bf16x8 av[2];
#pragma unroll
      for (int mf = 0; mf < 2; ++mf)
        av[mf] = *(const bf16x8*)&VrT[(32 * w + 16 * mf + ml) * 40 + 8 * gq];
#pragma unroll
      for (int nf = 0; nf < 8; ++nf) {
        bf16x8 bv = *(const bf16x8*)&KnT[(16 * nf + ml) * 40 + 8 * gq];
#pragma unroll
        for (int mf = 0; mf < 2; ++mf)
          acc[mf][nf] = __builtin_amdgcn_mfma_f32_16x16x32_bf16(av[mf], bv, acc[mf][nf], 0, 0, 0);
      }
    }
  }
  // epilogue: atomic accumulate into kvT f32
  float* kvp = kvt + (b * Kn + k) * Cn * Cn;
#pragma unroll
  for (int mf = 0; mf < 2; ++mf)
#pragma unroll
    for (int nf = 0; nf < 8; ++nf) {
      int c = 16 * nf + ml;
#pragma unroll
      for (int r = 0; r < 4; ++r) {
        int d = 32 * w + 16 * mf + 4 * gq + r;
        atomicAdd(&kvp[d * Cn + c], acc[mf][nf][r]);
      }
    }
}

// ---------------- K2b: kvT f32 -> bf16 ----------------
__global__ __launch_bounds__(256) void k2b_cvt(float* ws) {
  const float* src = ws + OFF_KVT32;
  unsigned short* dst = (unsigned short*)(ws + OFF_KVTBF);
  int i = blockIdx.x * 256 + threadIdx.x;
  float4 a = *(const float4*)&src[i * 8];
  float4 c = *(const float4*)&src[i * 8 + 4];
  union { unsigned short us[8]; uint4 u4; } o;
  o.us[0] = f2bf(a.x); o.us[1] = f2bf(a.y); o.us[2] = f2bf(a.z); o.us[3] = f2bf(a.w);
  o.us[4] = f2bf(c.x); o.us[5] = f2bf(c.y); o.us[6] = f2bf(c.z); o.us[7] = f2bf(c.w);
  *(uint4*)&dst[i * 8] = o.u4;
}

// ---------------- K3: agg partials via gathered MFMA GEMM ----------------
__global__ __launch_bounds__(256, 4) void k3_agg(const int* __restrict__ idxp, float* ws) {
  __shared__ __align__(16) unsigned short qt[32 * 136];  // [n][c], stride 136
  const unsigned short* Qnbf = (const unsigned short*)(ws + OFF_QNBF);
  const unsigned short* kvtbf = (const unsigned short*)(ws + OFF_KVTBF);
  int flag = ((const int*)(ws + OFF_FLAG))[0];

  int bid = blockIdx.x;
  int kh = bid & 1;
  int nt = (bid >> 1) & 127;
  int b = bid >> 8;
  int n0 = nt * 32;
  int t = threadIdx.x;
  int w = t >> 6, l = t & 63;
  int ml = l & 15, gq = l >> 4;

  f32x4 acc[2][2];
#pragma unroll
  for (int i = 0; i < 2; ++i)
#pragma unroll
    for (int j = 0; j < 2; ++j) acc[i][j] = (f32x4)0.f;

  for (int kk = 0; kk < 8; ++kk) {
    int k = kh * 8 + kk;
    __syncthreads();
    // stage gathered Qn rows
#pragma unroll
    for (int i = 0; i < 2; ++i) {
      int id = t + 256 * i;
      int row = id >> 4, c16 = id & 15;
      int fidx = (b * Nn + n0 + row) * Kn + k;
      int jn = flag ? idxp[2 * fidx] : idxp[fidx];
      uint4 v = *(const uint4*)&Qnbf[(b * Nn + jn) * Cn + c16 * 8];
      *(uint4*)&qt[row * 136 + c16 * 8] = v;
    }
    __syncthreads();
    const unsigned short* kvp = &kvtbf[(b * Kn + k) * Cn * Cn];
#pragma unroll
    for (int c0 = 0; c0 < 128; c0 += 32) {
      bf16x8 a0 = *(const bf16x8*)&qt[ml * 136 + c0 + 8 * gq];
      bf16x8 a1 = *(const bf16x8*)&qt[(ml + 16) * 136 + c0 + 8 * gq];
#pragma unroll
      for (int nf = 0; nf < 2; ++nf) {
        int d = 32 * w + 16 * nf + ml;
        bf16x8 bv = *(const bf16x8*)&kvp[d * Cn + c0 + 8 * gq];
        acc[0][nf] = __builtin_amdgcn_mfma_f32_16x16x32_bf16(a0, bv, acc[0][nf], 0, 0, 0);
        acc[1][nf] = __builtin_amdgcn_mfma_f32_16x16x32_bf16(a1, bv, acc[1][nf], 0, 0, 0);
      }
    }
  }
  float* ag = ws + (kh ? OFF_VM : OFF_AGG0);
#pragma unroll
  for (int mf = 0; mf < 2; ++mf)
#pragma unroll
    for (int nf = 0; nf < 2; ++nf) {
      int d = 32 * w + 16 * nf + ml;
#pragma unroll
      for (int r = 0; r < 4; ++r) {
        int n = n0 + 16 * mf + 4 * gq + r;
        ag[(b * Nn + n) * Cn + d] = acc[mf][nf][r];
      }
    }
}

// ---------------- K4: out = relu(agg@Wm1^T+bm1)@Wm2^T + bm2 + xt ----------------
__global__ __launch_bounds__(256, 2) void k4_mlp(const float* __restrict__ x,
                                                 const float* __restrict__ bm1,
                                                 const float* __restrict__ bm2,
                                                 float* __restrict__ out, float* ws) {
  __shared__ float a_s[32 * 132];
  __shared__ float h_s[32 * 132];   // reused as out_s[128*33]
  const float* agg0 = ws + OFF_AGG0;
  const float* agg1 = ws + OFF_VM;
  const float* Wm1T = ws + OFF_WM1T;
  const float* Wm2T = ws + OFF_WM2T;
  const float invN = 1.f / (float)Nn;
  int b = blockIdx.x >> 7;
  int n0 = (blockIdx.x & 127) << 5;
  int t = threadIdx.x;
  int tn = t >> 4, td = t & 15;
#pragma unroll
  for (int i = 0; i < 4; ++i) {
    int f4 = t + 256 * i;
    int row = f4 >> 5, c4 = f4 & 31;
    int off = (b * Nn + n0 + row) * Cn + c4 * 4;
    float4 v0 = *(const float4*)&agg0[off];
    float4 v1 = *(const float4*)&agg1[off];
    float4 v = {(v0.x + v1.x) * invN, (v0.y + v1.y) * invN, (v0.z + v1.z) * invN, (v0.w + v1.w) * invN};
    *(float4*)&a_s[row * 132 + c4 * 4] = v;
  }
  __syncthreads();
  float oacc[2][8];
#pragma unroll
  for (int ii = 0; ii < 2; ++ii)
#pragma unroll
    for (int jj = 0; jj < 8; ++jj) oacc[ii][jj] = bm2[td * 8 + jj];
  for (int hc = 0; hc < 512; hc += 128) {
    float hacc[2][8];
#pragma unroll
    for (int ii = 0; ii < 2; ++ii)
#pragma unroll
      for (int jj = 0; jj < 8; ++jj) hacc[ii][jj] = bm1[hc + td * 8 + jj];
#pragma unroll 4
    for (int c = 0; c < 128; ++c) {
      float a0 = a_s[tn * 132 + c];
      float a1 = a_s[(tn + 16) * 132 + c];
      const float* wp = &Wm1T[c * 512 + hc + td * 8];
      float4 w0 = *(const float4*)wp;
      float4 w1 = *(const float4*)(wp + 4);
      float w[8] = {w0.x, w0.y, w0.z, w0.w, w1.x, w1.y, w1.z, w1.w};
#pragma unroll
      for (int jj = 0; jj < 8; ++jj) {
        hacc[0][jj] = fmaf(a0, w[jj], hacc[0][jj]);
        hacc[1][jj] = fmaf(a1, w[jj], hacc[1][jj]);
      }
    }
    __syncthreads();
#pragma unroll
    for (int ii = 0; ii < 2; ++ii) {
      float4 hw0 = {fmaxf(hacc[ii][0], 0.f), fmaxf(hacc[ii][1], 0.f), fmaxf(hacc[ii][2], 0.f), fmaxf(hacc[ii][3], 0.f)};
      float4 hw1 = {fmaxf(hacc[ii][4], 0.f), fmaxf(hacc[ii][5], 0.f), fmaxf(hacc[ii][6], 0.f), fmaxf(hacc[ii][7], 0.f)};
      *(float4*)&h_s[(tn + 16 * ii) * 132 + td * 8] = hw0;
      *(float4*)&h_s[(tn + 16 * ii) * 132 + td * 8 + 4] = hw1;
    }
    __syncthreads();
#pragma unroll 4
    for (int hh = 0; hh < 128; ++hh) {
      float h0 = h_s[tn * 132 + hh];
      float h1 = h_s[(tn + 16) * 132 + hh];
      const float* wp2 = &Wm2T[(hc + hh) * 128 + td * 8];
      float4 w0 = *(const float4*)wp2;
      float4 w1 = *(const float4*)(wp2 + 4);
      float w[8] = {w0.x, w0.y, w0.z, w0.w, w1.x, w1.y, w1.z, w1.w};
#pragma unroll
      for (int jj = 0; jj < 8; ++jj) {
        oacc[0][jj] = fmaf(h0, w[jj], oacc[0][jj]);
        oacc[1][jj] = fmaf(h1, w[jj], oacc[1][jj]);
      }
    }
    __syncthreads();
  }
  float* out_s = h_s;
#pragma unroll
  for (int ii = 0; ii < 2; ++ii)
#pragma unroll
    for (int jj = 0; jj < 8; ++jj) out_s[(td * 8 + jj) * 33 + tn + 16 * ii] = oacc[ii][jj];
  __syncthreads();
#pragma unroll
  for (int i = 0; i < 16; ++i) {
    int id = t + 256 * i;
    int co = id >> 5, j = id & 31;
    out[(b * Cn + co) * Nn + n0 + j] = out_s[co * 33 + j] + x[(b * Cn + co) * Nn + n0 + j];
  }
}

extern "C" void kernel_launch(void* const* d_in, const int* in_sizes, int n_in,
                              void* d_out, int out_size, void* d_ws, size_t ws_size,
                              hipStream_t stream) {
  const float* pos  = (const float*)d_in[0];
  const float* x    = (const float*)d_in[1];
  const int*   idx  = (const int*)d_in[2];
  const float* dist = (const float*)d_in[3];
  const float* Wqkv = (const float*)d_in[4];
  const float* W1   = (const float*)d_in[5];
  const float* b1   = (const float*)d_in[6];
  const float* W2   = (const float*)d_in[7];
  const float* b2   = (const float*)d_in[8];
  const float* Wm1  = (const float*)d_in[9];
  const float* bm1  = (const float*)d_in[10];
  const float* Wm2  = (const float*)d_in[11];
  const float* bm2  = (const float*)d_in[12];
  float* out = (float*)d_out;
  float* ws = (float*)d_ws;

  hipMemsetAsync(ws + OFF_KVT32, 0, (size_t)Bn * Kn * Cn * Cn * sizeof(float), stream);
  hipLaunchKernelGGL(k0_prep, dim3(704), dim3(256), 0, stream, Wqkv, Wm1, Wm2, idx, ws);
  hipLaunchKernelGGL(k1_qkv, dim3(Bn * 64), dim3(256), 0, stream, x, ws);
  hipLaunchKernelGGL(k2_kv, dim3(Bn * Kn * CH2), dim3(256), 0, stream, pos, dist, idx, W1, b1, W2, b2, ws);
  hipLaunchKernelGGL(k2b_cvt, dim3(512), dim3(256), 0, stream, ws);
  hipLaunchKernelGGL(k3_agg, dim3(Bn * 2 * 128), dim3(256), 0, stream, idx, ws);
  hipLaunchKernelGGL(k4_mlp, dim3(Bn * 128), dim3(256), 0, stream, x, bm1, bm2, out, ws);
}

// Round 3
// 194.886 us; speedup vs baseline: 3.3901x; 1.6763x over previous
//
#include <hip/hip_runtime.h>
#include <math.h>

#define Bn 4
#define Nn 4096
#define Kn 16
#define Cn 128
#define HIDn 64

// ws layout (float offsets)
#define OFF_WQKVBF 0          // 49152 bf16 = 24576 f
#define OFF_WM1BF  24576      // 65536 bf16 = 32768 f
#define OFF_WM2BF  57344      // 65536 bf16 = 32768 f
#define OFF_QNBF   90112      // B*N*C bf16 = 1048576 f
#define OFF_KM     1138688    // B*N*C f32
#define OFF_VM     3235840    // B*N*C f32 (aliased as AGG1)
#define OFF_KVT32  5332992    // B*K*C*C f32 (atomic target, [b,k,d,c])
#define OFF_KVTBF  6381568    // B*K*C*C bf16 = 524288 f
#define OFF_AGG0   6905856    // B*N*C f32
#define OFF_FLAG   9003008    // 1 int

typedef short bf16x8 __attribute__((ext_vector_type(8)));
typedef float f32x4 __attribute__((ext_vector_type(4)));

__device__ inline unsigned short f2bf(float f) {
  union { float f; unsigned u; } v; v.f = f;
  unsigned r = v.u + 0x7fffu + ((v.u >> 16) & 1u);
  return (unsigned short)(r >> 16);
}

// ---------------- K0: weight bf16 casts + idx dtype probe ----------------
__global__ void k0_prep(const float* __restrict__ Wqkv,
                        const float* __restrict__ Wm1, const float* __restrict__ Wm2,
                        const int* __restrict__ idx_raw, float* ws) {
  if (blockIdx.x == 0 && threadIdx.x == 0) {
    int any = 0;
    for (int i = 0; i < 64; ++i) any |= idx_raw[2 * i + 1];
    ((int*)(ws + OFF_FLAG))[0] = (any == 0) ? 1 : 0;   // 1 => idx is int64
  }
  int t = blockIdx.x * 256 + threadIdx.x;
  if (t < 49152) { ((unsigned short*)(ws + OFF_WQKVBF))[t] = f2bf(Wqkv[t]); return; }
  t -= 49152;
  if (t < 65536) { ((unsigned short*)(ws + OFF_WM1BF))[t] = f2bf(Wm1[t]); return; }
  t -= 65536;
  if (t < 65536) { ((unsigned short*)(ws + OFF_WM2BF))[t] = f2bf(Wm2[t]); return; }
}

// ---------------- K1: qkv GEMM (MFMA); Q -> normalized bf16, K/V -> f32 ----------------
__global__ __launch_bounds__(256, 2) void k1_qkv(const float* __restrict__ x, float* ws) {
  __shared__ __align__(16) unsigned short a_lds[32 * 136];  // [n][c] bf16
  __shared__ __align__(16) float qkv_lds[32 * 388];         // [n][m] f32
  const unsigned short* Wq = (const unsigned short*)(ws + OFF_WQKVBF);
  unsigned short* Qnbf = (unsigned short*)(ws + OFF_QNBF);
  float* Km = ws + OFF_KM;
  float* Vm = ws + OFF_VM;
  int b = blockIdx.x >> 7;
  int n0 = (blockIdx.x & 127) << 5;
  int t = threadIdx.x;
  int w = t >> 6, l = t & 63, ml = l & 15, gq = l >> 4;
#pragma unroll
  for (int i = 0; i < 16; ++i) {
    int id = t + 256 * i;
    int c = id >> 5, j = id & 31;
    a_lds[j * 136 + c] = f2bf(x[(b * Cn + c) * Nn + n0 + j]);
  }
  __syncthreads();
  f32x4 acc[2][6];
#pragma unroll
  for (int i = 0; i < 2; ++i)
#pragma unroll
    for (int j = 0; j < 6; ++j) acc[i][j] = (f32x4)0.f;
#pragma unroll
  for (int kc = 0; kc < 4; ++kc) {
    bf16x8 av0 = *(const bf16x8*)&a_lds[ml * 136 + kc * 32 + 8 * gq];
    bf16x8 av1 = *(const bf16x8*)&a_lds[(ml + 16) * 136 + kc * 32 + 8 * gq];
#pragma unroll
    for (int nf = 0; nf < 6; ++nf) {
      int m = 96 * w + 16 * nf + ml;
      bf16x8 bv = *(const bf16x8*)&Wq[m * 128 + kc * 32 + 8 * gq];
      acc[0][nf] = __builtin_amdgcn_mfma_f32_16x16x32_bf16(av0, bv, acc[0][nf], 0, 0, 0);
      acc[1][nf] = __builtin_amdgcn_mfma_f32_16x16x32_bf16(av1, bv, acc[1][nf], 0, 0, 0);
    }
  }
#pragma unroll
  for (int mf = 0; mf < 2; ++mf)
#pragma unroll
    for (int nf = 0; nf < 6; ++nf)
#pragma unroll
      for (int r = 0; r < 4; ++r)
        qkv_lds[(16 * mf + 4 * gq + r) * 388 + 96 * w + 16 * nf + ml] = acc[mf][nf][r];
  __syncthreads();
  // Q normalize -> bf16
  {
    int g = t >> 3, l8 = t & 7;
    float4 q4[4];
    float ss = 0.f;
#pragma unroll
    for (int q = 0; q < 4; ++q) {
      q4[q] = *(const float4*)&qkv_lds[g * 388 + l8 * 16 + 4 * q];
      ss = fmaf(q4[q].x, q4[q].x, ss); ss = fmaf(q4[q].y, q4[q].y, ss);
      ss = fmaf(q4[q].z, q4[q].z, ss); ss = fmaf(q4[q].w, q4[q].w, ss);
    }
    ss += __shfl_xor(ss, 1); ss += __shfl_xor(ss, 2); ss += __shfl_xor(ss, 4);
    float sc = 1.f / fmaxf(sqrtf(ss), 1e-12f);
    union { unsigned short us[8]; uint4 u4; } o0, o1;
#pragma unroll
    for (int q = 0; q < 2; ++q) {
      o0.us[q * 4 + 0] = f2bf(q4[q].x * sc); o0.us[q * 4 + 1] = f2bf(q4[q].y * sc);
      o0.us[q * 4 + 2] = f2bf(q4[q].z * sc); o0.us[q * 4 + 3] = f2bf(q4[q].w * sc);
    }
#pragma unroll
    for (int q = 0; q < 2; ++q) {
      o1.us[q * 4 + 0] = f2bf(q4[2 + q].x * sc); o1.us[q * 4 + 1] = f2bf(q4[2 + q].y * sc);
      o1.us[q * 4 + 2] = f2bf(q4[2 + q].z * sc); o1.us[q * 4 + 3] = f2bf(q4[2 + q].w * sc);
    }
    *(uint4*)&Qnbf[(b * Nn + n0 + g) * Cn + l8 * 16] = o0.u4;
    *(uint4*)&Qnbf[(b * Nn + n0 + g) * Cn + l8 * 16 + 8] = o1.u4;
  }
  // K, V copy-out f32
#pragma unroll
  for (int i = 0; i < 4; ++i) {
    int id = t + 256 * i;
    int row = id >> 5, c4 = id & 31;
    float4 vk = *(const float4*)&qkv_lds[row * 388 + 128 + c4 * 4];
    float4 vv = *(const float4*)&qkv_lds[row * 388 + 256 + c4 * 4];
    *(float4*)&Km[(b * Nn + n0 + row) * Cn + c4 * 4] = vk;
    *(float4*)&Vm[(b * Nn + n0 + row) * Cn + c4 * 4] = vv;
  }
}

// ---------------- K2: kvT[b,k,d,c] += sum_n Vrel[n,d]*Knorm[n,c]  (MFMA) ----------------
#define CH2 8
__global__ __launch_bounds__(256, 2) void k2_kv(const float* __restrict__ pos,
                                                const float* __restrict__ dist,
                                                const int* __restrict__ idxp,
                                                const float* __restrict__ W1,
                                                const float* __restrict__ b1,
                                                const float* __restrict__ W2,
                                                const float* __restrict__ b2,
                                                float* ws) {
  __shared__ __align__(16) unsigned short W2bf[128 * 72];  // [c][h], stride 72
  __shared__ __align__(16) unsigned short h_lds[32 * 72];  // [n][h], stride 72
  __shared__ float pe_lds[32 * 132];                        // [n][c]
  __shared__ __align__(16) unsigned short KnT[128 * 40];   // [c][n], stride 40
  __shared__ __align__(16) unsigned short VrT[128 * 40];   // [d][n], stride 40
  __shared__ float W1s[640];
  __shared__ float b1s[64];
  __shared__ float b2s[128];
  __shared__ int jn_s[32];

  const float* Km = ws + OFF_KM;
  const float* Vm = ws + OFF_VM;
  float* kvt = ws + OFF_KVT32;
  int flag = ((const int*)(ws + OFF_FLAG))[0];

  int bid = blockIdx.x;
  int ch = bid & (CH2 - 1);
  int bk = bid / CH2;
  int k = bk & 15, b = bk >> 4;
  int t = threadIdx.x;
  int w = t >> 6, l = t & 63;
  int ml = l & 15, gq = l >> 4;

#pragma unroll
  for (int i = 0; i < 32; ++i) {
    int id = t + 256 * i;
    int c = id >> 6, h = id & 63;
    W2bf[c * 72 + h] = f2bf(W2[c * 64 + h]);
  }
  for (int i = t; i < 640; i += 256) W1s[i] = W1[i];
  if (t < 64) b1s[t] = b1[t];
  if (t < 128) b2s[t] = b2[t];

  f32x4 acc[2][8];
#pragma unroll
  for (int i = 0; i < 2; ++i)
#pragma unroll
    for (int j = 0; j < 8; ++j) acc[i][j] = (f32x4)0.f;

  int g = t >> 3, l8 = t & 7;      // phase A
  int tn2 = t >> 5, td = t & 31;   // phase B2

  for (int it = 0; it < 16; ++it) {
    int n0 = ch * 512 + it * 32;
    __syncthreads();
    // ---- Phase A: feat10 + MLP layer1 -> h_lds bf16 ----
    {
      int n = n0 + g;
      int fidx = (b * Nn + n) * Kn + k;
      int jn = flag ? idxp[2 * fidx] : idxp[fidx];
      if (l8 == 0) jn_s[g] = jn;
      float dd = dist[fidx];
      float pc0 = pos[(b * Nn + n) * 3 + 0], pc1 = pos[(b * Nn + n) * 3 + 1], pc2 = pos[(b * Nn + n) * 3 + 2];
      float pn0 = pos[(b * Nn + jn) * 3 + 0], pn1 = pos[(b * Nn + jn) * 3 + 1], pn2 = pos[(b * Nn + jn) * 3 + 2];
      float f10[10] = {pc0, pc1, pc2, pn0, pn1, pn2, pc0 - pn0, pc1 - pn1, pc2 - pn2, dd};
      union { unsigned short us[8]; uint4 u4; } hv;
#pragma unroll
      for (int oo = 0; oo < 8; ++oo) {
        int o = l8 * 8 + oo;
        float a = b1s[o];
#pragma unroll
        for (int i2 = 0; i2 < 10; ++i2) a = fmaf(W1s[o * 10 + i2], f10[i2], a);
        hv.us[oo] = f2bf(fmaxf(a, 0.f));
      }
      *(uint4*)&h_lds[g * 72 + l8 * 8] = hv.u4;
    }
    __syncthreads();
    // ---- Phase B1 (MFMA): pe[n][c] = h @ W2^T ----
    {
      f32x4 pacc[2][2];
#pragma unroll
      for (int i = 0; i < 2; ++i)
#pragma unroll
        for (int j = 0; j < 2; ++j) pacc[i][j] = (f32x4)0.f;
#pragma unroll
      for (int hc = 0; hc < 64; hc += 32) {
        bf16x8 av[2];
#pragma unroll
        for (int mf = 0; mf < 2; ++mf)
          av[mf] = *(const bf16x8*)&h_lds[(ml + 16 * mf) * 72 + hc + 8 * gq];
#pragma unroll
        for (int nf = 0; nf < 2; ++nf) {
          int c = 32 * w + 16 * nf + ml;
          bf16x8 bv = *(const bf16x8*)&W2bf[c * 72 + hc + 8 * gq];
          pacc[0][nf] = __builtin_amdgcn_mfma_f32_16x16x32_bf16(av[0], bv, pacc[0][nf], 0, 0, 0);
          pacc[1][nf] = __builtin_amdgcn_mfma_f32_16x16x32_bf16(av[1], bv, pacc[1][nf], 0, 0, 0);
        }
      }
#pragma unroll
      for (int mf = 0; mf < 2; ++mf)
#pragma unroll
        for (int nf = 0; nf < 2; ++nf) {
          int c = 32 * w + 16 * nf + ml;
          float b2v = b2s[c];
#pragma unroll
          for (int r = 0; r < 4; ++r)
            pe_lds[(16 * mf + 4 * gq + r) * 132 + c] = pacc[mf][nf][r] + b2v;
        }
    }
    __syncthreads();
    // ---- Phase B2: gather K/V + pe, normalize, write transposed bf16 tiles ----
    {
      unsigned short kout[4][4], vout[4][4];
#pragma unroll
      for (int ii = 0; ii < 4; ++ii) {
        int nn = tn2 * 4 + ii;
        int jn = jn_s[nn];
        const float* krow = &Km[(b * Nn + jn) * Cn];
        const float* vrow = &Vm[(b * Nn + jn) * Cn];
        float kr[4], vr[4];
        float ss = 0.f;
#pragma unroll
        for (int q = 0; q < 4; ++q) {
          int c = 32 * q + td;
          float pe = pe_lds[nn * 132 + c];
          kr[q] = krow[c] + pe;
          vr[q] = fmaxf(vrow[c] + pe, 0.f);
          ss = fmaf(kr[q], kr[q], ss);
        }
        ss += __shfl_xor(ss, 1); ss += __shfl_xor(ss, 2); ss += __shfl_xor(ss, 4);
        ss += __shfl_xor(ss, 8); ss += __shfl_xor(ss, 16);
        float sc = 1.f / fmaxf(sqrtf(ss), 1e-12f);
#pragma unroll
        for (int q = 0; q < 4; ++q) {
          kout[q][ii] = f2bf(kr[q] * sc);
          vout[q][ii] = f2bf(vr[q]);
        }
      }
#pragma unroll
      for (int q = 0; q < 4; ++q) {
        int c = 32 * q + td;
        union { unsigned short us[4]; uint2 u2; } ku, vu;
#pragma unroll
        for (int ii = 0; ii < 4; ++ii) { ku.us[ii] = kout[q][ii]; vu.us[ii] = vout[q][ii]; }
        *(uint2*)&KnT[c * 40 + tn2 * 4] = ku.u2;
        *(uint2*)&VrT[c * 40 + tn2 * 4] = vu.u2;
      }
    }
    __syncthreads();
    // ---- Phase C (MFMA): kvT[d][c] += VrT[d][:] * KnT[c][:] ----
    {
      bf16x8 av[2];
#pragma unroll
      for (int mf = 0; mf < 2; ++mf)
        av[mf] = *(const bf16x8*)&VrT[(32 * w + 16 * mf + ml) * 40 + 8 * gq];
#pragma unroll
      for (int nf = 0; nf < 8; ++nf) {
        bf16x8 bv = *(const bf16x8*)&KnT[(16 * nf + ml) * 40 + 8 * gq];
#pragma unroll
        for (int mf = 0; mf < 2; ++mf)
          acc[mf][nf] = __builtin_amdgcn_mfma_f32_16x16x32_bf16(av[mf], bv, acc[mf][nf], 0, 0, 0);
      }
    }
  }
  float* kvp = kvt + (b * Kn + k) * Cn * Cn;
#pragma unroll
  for (int mf = 0; mf < 2; ++mf)
#pragma unroll
    for (int nf = 0; nf < 8; ++nf) {
      int c = 16 * nf + ml;
#pragma unroll
      for (int r = 0; r < 4; ++r) {
        int d = 32 * w + 16 * mf + 4 * gq + r;
        atomicAdd(&kvp[d * Cn + c], acc[mf][nf][r]);
      }
    }
}

// ---------------- K2b: kvT f32 -> bf16 ----------------
__global__ __launch_bounds__(256) void k2b_cvt(float* ws) {
  const float* src = ws + OFF_KVT32;
  unsigned short* dst = (unsigned short*)(ws + OFF_KVTBF);
  int i = blockIdx.x * 256 + threadIdx.x;
  float4 a = *(const float4*)&src[i * 8];
  float4 c = *(const float4*)&src[i * 8 + 4];
  union { unsigned short us[8]; uint4 u4; } o;
  o.us[0] = f2bf(a.x); o.us[1] = f2bf(a.y); o.us[2] = f2bf(a.z); o.us[3] = f2bf(a.w);
  o.us[4] = f2bf(c.x); o.us[5] = f2bf(c.y); o.us[6] = f2bf(c.z); o.us[7] = f2bf(c.w);
  *(uint4*)&dst[i * 8] = o.u4;
}

// ---------------- K3: agg partials via gathered MFMA GEMM ----------------
__global__ __launch_bounds__(256, 4) void k3_agg(const int* __restrict__ idxp, float* ws) {
  __shared__ __align__(16) unsigned short qt[32 * 136];  // [n][c]
  const unsigned short* Qnbf = (const unsigned short*)(ws + OFF_QNBF);
  const unsigned short* kvtbf = (const unsigned short*)(ws + OFF_KVTBF);
  int flag = ((const int*)(ws + OFF_FLAG))[0];

  int bid = blockIdx.x;
  int kh = bid & 1;
  int nt = (bid >> 1) & 127;
  int b = bid >> 8;
  int n0 = nt * 32;
  int t = threadIdx.x;
  int w = t >> 6, l = t & 63;
  int ml = l & 15, gq = l >> 4;

  f32x4 acc[2][2];
#pragma unroll
  for (int i = 0; i < 2; ++i)
#pragma unroll
    for (int j = 0; j < 2; ++j) acc[i][j] = (f32x4)0.f;

  for (int kk = 0; kk < 8; ++kk) {
    int k = kh * 8 + kk;
    __syncthreads();
#pragma unroll
    for (int i = 0; i < 2; ++i) {
      int id = t + 256 * i;
      int row = id >> 4, c16 = id & 15;
      int fidx = (b * Nn + n0 + row) * Kn + k;
      int jn = flag ? idxp[2 * fidx] : idxp[fidx];
      uint4 v = *(const uint4*)&Qnbf[(b * Nn + jn) * Cn + c16 * 8];
      *(uint4*)&qt[row * 136 + c16 * 8] = v;
    }
    __syncthreads();
    const unsigned short* kvp = &kvtbf[(b * Kn + k) * Cn * Cn];
#pragma unroll
    for (int c0 = 0; c0 < 128; c0 += 32) {
      bf16x8 a0 = *(const bf16x8*)&qt[ml * 136 + c0 + 8 * gq];
      bf16x8 a1 = *(const bf16x8*)&qt[(ml + 16) * 136 + c0 + 8 * gq];
#pragma unroll
      for (int nf = 0; nf < 2; ++nf) {
        int d = 32 * w + 16 * nf + ml;
        bf16x8 bv = *(const bf16x8*)&kvp[d * Cn + c0 + 8 * gq];
        acc[0][nf] = __builtin_amdgcn_mfma_f32_16x16x32_bf16(a0, bv, acc[0][nf], 0, 0, 0);
        acc[1][nf] = __builtin_amdgcn_mfma_f32_16x16x32_bf16(a1, bv, acc[1][nf], 0, 0, 0);
      }
    }
  }
  float* ag = ws + (kh ? OFF_VM : OFF_AGG0);
#pragma unroll
  for (int mf = 0; mf < 2; ++mf)
#pragma unroll
    for (int nf = 0; nf < 2; ++nf) {
      int d = 32 * w + 16 * nf + ml;
#pragma unroll
      for (int r = 0; r < 4; ++r) {
        int n = n0 + 16 * mf + 4 * gq + r;
        ag[(b * Nn + n) * Cn + d] = acc[mf][nf][r];
      }
    }
}

// ---------------- K4: out = relu(agg@Wm1^T+bm1)@Wm2^T + bm2 + xt  (MFMA) ----------------
__global__ __launch_bounds__(256, 2) void k4_mlp(const float* __restrict__ x,
                                                 const float* __restrict__ bm1,
                                                 const float* __restrict__ bm2,
                                                 float* __restrict__ out, float* ws) {
  __shared__ __align__(16) unsigned short a_lds[32 * 136];  // [n][c] bf16
  __shared__ __align__(16) unsigned short h_lds[32 * 520];  // [n][h] bf16
  __shared__ float out_s[128 * 33];                          // [co][n]
  const float* agg0 = ws + OFF_AGG0;
  const float* agg1 = ws + OFF_VM;
  const unsigned short* Wm1bf = (const unsigned short*)(ws + OFF_WM1BF);
  const unsigned short* Wm2bf = (const unsigned short*)(ws + OFF_WM2BF);
  const float invN = 1.f / (float)Nn;
  int b = blockIdx.x >> 7;
  int n0 = (blockIdx.x & 127) << 5;
  int t = threadIdx.x;
  int w = t >> 6, l = t & 63, ml = l & 15, gq = l >> 4;
  // stage agg (sum partials, scale, cvt)
#pragma unroll
  for (int i = 0; i < 4; ++i) {
    int id = t + 256 * i;
    int row = id >> 5, c4 = id & 31;
    int off = (b * Nn + n0 + row) * Cn + c4 * 4;
    float4 v0 = *(const float4*)&agg0[off];
    float4 v1 = *(const float4*)&agg1[off];
    union { unsigned short us[4]; uint2 u2; } o;
    o.us[0] = f2bf((v0.x + v1.x) * invN); o.us[1] = f2bf((v0.y + v1.y) * invN);
    o.us[2] = f2bf((v0.z + v1.z) * invN); o.us[3] = f2bf((v0.w + v1.w) * invN);
    *(uint2*)&a_lds[row * 136 + c4 * 4] = o.u2;
  }
  __syncthreads();
  // layer1: wave w -> h cols [128w, 128w+128)
  {
    f32x4 hacc[2][8];
#pragma unroll
    for (int i = 0; i < 2; ++i)
#pragma unroll
      for (int j = 0; j < 8; ++j) hacc[i][j] = (f32x4)0.f;
#pragma unroll
    for (int kc = 0; kc < 4; ++kc) {
      bf16x8 av0 = *(const bf16x8*)&a_lds[ml * 136 + kc * 32 + 8 * gq];
      bf16x8 av1 = *(const bf16x8*)&a_lds[(ml + 16) * 136 + kc * 32 + 8 * gq];
#pragma unroll
      for (int nf = 0; nf < 8; ++nf) {
        int h = 128 * w + 16 * nf + ml;
        bf16x8 bv = *(const bf16x8*)&Wm1bf[h * 128 + kc * 32 + 8 * gq];
        hacc[0][nf] = __builtin_amdgcn_mfma_f32_16x16x32_bf16(av0, bv, hacc[0][nf], 0, 0, 0);
        hacc[1][nf] = __builtin_amdgcn_mfma_f32_16x16x32_bf16(av1, bv, hacc[1][nf], 0, 0, 0);
      }
    }
#pragma unroll
    for (int mf = 0; mf < 2; ++mf)
#pragma unroll
      for (int nf = 0; nf < 8; ++nf) {
        int h = 128 * w + 16 * nf + ml;
        float bias = bm1[h];
#pragma unroll
        for (int r = 0; r < 4; ++r)
          h_lds[(16 * mf + 4 * gq + r) * 520 + h] = f2bf(fmaxf(hacc[mf][nf][r] + bias, 0.f));
      }
  }
  __syncthreads();
  // layer2: wave w -> co cols [32w, 32w+32)
  {
    f32x4 oacc[2][2];
#pragma unroll
    for (int i = 0; i < 2; ++i)
#pragma unroll
      for (int j = 0; j < 2; ++j) oacc[i][j] = (f32x4)0.f;
#pragma unroll
    for (int kc = 0; kc < 16; ++kc) {
      bf16x8 av0 = *(const bf16x8*)&h_lds[ml * 520 + kc * 32 + 8 * gq];
      bf16x8 av1 = *(const bf16x8*)&h_lds[(ml + 16) * 520 + kc * 32 + 8 * gq];
#pragma unroll
      for (int nf = 0; nf < 2; ++nf) {
        int co = 32 * w + 16 * nf + ml;
        bf16x8 bv = *(const bf16x8*)&Wm2bf[co * 512 + kc * 32 + 8 * gq];
        oacc[0][nf] = __builtin_amdgcn_mfma_f32_16x16x32_bf16(av0, bv, oacc[0][nf], 0, 0, 0);
        oacc[1][nf] = __builtin_amdgcn_mfma_f32_16x16x32_bf16(av1, bv, oacc[1][nf], 0, 0, 0);
      }
    }
#pragma unroll
    for (int mf = 0; mf < 2; ++mf)
#pragma unroll
      for (int nf = 0; nf < 2; ++nf) {
        int co = 32 * w + 16 * nf + ml;
        float bias = bm2[co];
#pragma unroll
        for (int r = 0; r < 4; ++r)
          out_s[co * 33 + 16 * mf + 4 * gq + r] = oacc[mf][nf][r] + bias;
      }
  }
  __syncthreads();
#pragma unroll
  for (int i = 0; i < 16; ++i) {
    int id = t + 256 * i;
    int co = id >> 5, j = id & 31;
    out[(b * Cn + co) * Nn + n0 + j] = out_s[co * 33 + j] + x[(b * Cn + co) * Nn + n0 + j];
  }
}

extern "C" void kernel_launch(void* const* d_in, const int* in_sizes, int n_in,
                              void* d_out, int out_size, void* d_ws, size_t ws_size,
                              hipStream_t stream) {
  const float* pos  = (const float*)d_in[0];
  const float* x    = (const float*)d_in[1];
  const int*   idx  = (const int*)d_in[2];
  const float* dist = (const float*)d_in[3];
  const float* Wqkv = (const float*)d_in[4];
  const float* W1   = (const float*)d_in[5];
  const float* b1   = (const float*)d_in[6];
  const float* W2   = (const float*)d_in[7];
  const float* b2   = (const float*)d_in[8];
  const float* Wm1  = (const float*)d_in[9];
  const float* bm1  = (const float*)d_in[10];
  const float* Wm2  = (const float*)d_in[11];
  const float* bm2  = (const float*)d_in[12];
  float* out = (float*)d_out;
  float* ws = (float*)d_ws;

  hipMemsetAsync(ws + OFF_KVT32, 0, (size_t)Bn * Kn * Cn * Cn * sizeof(float), stream);
  hipLaunchKernelGGL(k0_prep, dim3(704), dim3(256), 0, stream, Wqkv, Wm1, Wm2, idx, ws);
  hipLaunchKernelGGL(k1_qkv, dim3(Bn * 128), dim3(256), 0, stream, x, ws);
  hipLaunchKernelGGL(k2_kv, dim3(Bn * Kn * CH2), dim3(256), 0, stream, pos, dist, idx, W1, b1, W2, b2, ws);
  hipLaunchKernelGGL(k2b_cvt, dim3(512), dim3(256), 0, stream, ws);
  hipLaunchKernelGGL(k3_agg, dim3(Bn * 2 * 128), dim3(256), 0, stream, idx, ws);
  hipLaunchKernelGGL(k4_mlp, dim3(Bn * 128), dim3(256), 0, stream, x, bm1, bm2, out, ws);
}

// Round 5
// 177.179 us; speedup vs baseline: 3.7289x; 1.0999x over previous
//
#include <hip/hip_runtime.h>
#include <math.h>

#define Bn 4
#define Nn 4096
#define Kn 16
#define Cn 128
#define HIDn 64

// ws layout (float offsets) — bf16 [B,N,C] buffers are 2,097,152 elems = 1,048,576 floats
#define OFF_WQKVBF 0          // 49152 bf16 = 24576 f
#define OFF_WM1BF  24576      // 65536 bf16 = 32768 f
#define OFF_WM2BF  57344      // 65536 bf16 = 32768 f
#define OFF_W2BFG  90112      // 8192 bf16 = 4096 f
#define OFF_QNBF   94208      // 1048576 f
#define OFF_KMBF   1142784    // 1048576 f
#define OFF_VMBF   2191360    // 1048576 f
#define OFF_KVT32  3239936    // B*K*C*C f32 = 1048576 f  (atomic target, [b,k,d,c])
#define OFF_KVTBF  4288512    // 524288 f
#define OFF_AGG0   4812800    // 2097152 f
#define OFF_AGG1   6909952    // 2097152 f
#define OFF_FLAG   9007104    // 1 int

typedef short bf16x8 __attribute__((ext_vector_type(8)));
typedef float f32x4 __attribute__((ext_vector_type(4)));

__device__ inline unsigned short f2bf(float f) {
  union { float f; unsigned u; } v; v.f = f;
  unsigned r = v.u + 0x7fffu + ((v.u >> 16) & 1u);
  return (unsigned short)(r >> 16);
}
__device__ inline float b2f(unsigned short s) {
  union { unsigned u; float f; } v; v.u = ((unsigned)s) << 16; return v.f;
}

// ---------------- K0: weight bf16 casts + idx dtype probe ----------------
__global__ void k0_prep(const float* __restrict__ Wqkv,
                        const float* __restrict__ Wm1, const float* __restrict__ Wm2,
                        const float* __restrict__ W2,
                        const int* __restrict__ idx_raw, float* ws) {
  if (blockIdx.x == 0 && threadIdx.x == 0) {
    int any = 0;
    for (int i = 0; i < 64; ++i) any |= idx_raw[2 * i + 1];
    ((int*)(ws + OFF_FLAG))[0] = (any == 0) ? 1 : 0;   // 1 => idx is int64
  }
  int t = blockIdx.x * 256 + threadIdx.x;
  if (t < 49152) { ((unsigned short*)(ws + OFF_WQKVBF))[t] = f2bf(Wqkv[t]); return; }
  t -= 49152;
  if (t < 65536) { ((unsigned short*)(ws + OFF_WM1BF))[t] = f2bf(Wm1[t]); return; }
  t -= 65536;
  if (t < 65536) { ((unsigned short*)(ws + OFF_WM2BF))[t] = f2bf(Wm2[t]); return; }
  t -= 65536;
  if (t < 8192) { ((unsigned short*)(ws + OFF_W2BFG))[t] = f2bf(W2[t]); return; }
}

// ---------------- K1: qkv GEMM (MFMA); Q -> normalized bf16, K/V -> bf16 ----------------
__global__ __launch_bounds__(256, 2) void k1_qkv(const float* __restrict__ x, float* ws) {
  __shared__ __align__(16) unsigned short a_lds[32 * 136];  // [n][c] bf16
  __shared__ __align__(16) float qkv_lds[32 * 388];         // [n][m] f32
  const unsigned short* Wq = (const unsigned short*)(ws + OFF_WQKVBF);
  unsigned short* Qnbf = (unsigned short*)(ws + OFF_QNBF);
  unsigned short* KmBF = (unsigned short*)(ws + OFF_KMBF);
  unsigned short* VmBF = (unsigned short*)(ws + OFF_VMBF);
  int b = blockIdx.x >> 7;
  int n0 = (blockIdx.x & 127) << 5;
  int t = threadIdx.x;
  int w = t >> 6, l = t & 63, ml = l & 15, gq = l >> 4;
#pragma unroll
  for (int i = 0; i < 16; ++i) {
    int id = t + 256 * i;
    int c = id >> 5, j = id & 31;
    a_lds[j * 136 + c] = f2bf(x[(b * Cn + c) * Nn + n0 + j]);
  }
  __syncthreads();
  f32x4 acc[2][6];
#pragma unroll
  for (int i = 0; i < 2; ++i)
#pragma unroll
    for (int j = 0; j < 6; ++j) acc[i][j] = (f32x4)0.f;
#pragma unroll
  for (int kc = 0; kc < 4; ++kc) {
    bf16x8 av0 = *(const bf16x8*)&a_lds[ml * 136 + kc * 32 + 8 * gq];
    bf16x8 av1 = *(const bf16x8*)&a_lds[(ml + 16) * 136 + kc * 32 + 8 * gq];
#pragma unroll
    for (int nf = 0; nf < 6; ++nf) {
      int m = 96 * w + 16 * nf + ml;
      bf16x8 bv = *(const bf16x8*)&Wq[m * 128 + kc * 32 + 8 * gq];
      acc[0][nf] = __builtin_amdgcn_mfma_f32_16x16x32_bf16(av0, bv, acc[0][nf], 0, 0, 0);
      acc[1][nf] = __builtin_amdgcn_mfma_f32_16x16x32_bf16(av1, bv, acc[1][nf], 0, 0, 0);
    }
  }
#pragma unroll
  for (int mf = 0; mf < 2; ++mf)
#pragma unroll
    for (int nf = 0; nf < 6; ++nf)
#pragma unroll
      for (int r = 0; r < 4; ++r)
        qkv_lds[(16 * mf + 4 * gq + r) * 388 + 96 * w + 16 * nf + ml] = acc[mf][nf][r];
  __syncthreads();
  // Q normalize -> bf16
  {
    int g = t >> 3, l8 = t & 7;
    float4 q4[4];
    float ss = 0.f;
#pragma unroll
    for (int q = 0; q < 4; ++q) {
      q4[q] = *(const float4*)&qkv_lds[g * 388 + l8 * 16 + 4 * q];
      ss = fmaf(q4[q].x, q4[q].x, ss); ss = fmaf(q4[q].y, q4[q].y, ss);
      ss = fmaf(q4[q].z, q4[q].z, ss); ss = fmaf(q4[q].w, q4[q].w, ss);
    }
    ss += __shfl_xor(ss, 1); ss += __shfl_xor(ss, 2); ss += __shfl_xor(ss, 4);
    float sc = 1.f / fmaxf(sqrtf(ss), 1e-12f);
    union { unsigned short us[8]; uint4 u4; } o0, o1;
#pragma unroll
    for (int q = 0; q < 2; ++q) {
      o0.us[q * 4 + 0] = f2bf(q4[q].x * sc); o0.us[q * 4 + 1] = f2bf(q4[q].y * sc);
      o0.us[q * 4 + 2] = f2bf(q4[q].z * sc); o0.us[q * 4 + 3] = f2bf(q4[q].w * sc);
    }
#pragma unroll
    for (int q = 0; q < 2; ++q) {
      o1.us[q * 4 + 0] = f2bf(q4[2 + q].x * sc); o1.us[q * 4 + 1] = f2bf(q4[2 + q].y * sc);
      o1.us[q * 4 + 2] = f2bf(q4[2 + q].z * sc); o1.us[q * 4 + 3] = f2bf(q4[2 + q].w * sc);
    }
    *(uint4*)&Qnbf[(b * Nn + n0 + g) * Cn + l8 * 16] = o0.u4;
    *(uint4*)&Qnbf[(b * Nn + n0 + g) * Cn + l8 * 16 + 8] = o1.u4;
  }
  // K, V copy-out bf16
#pragma unroll
  for (int i = 0; i < 2; ++i) {
    int id = t + 256 * i;
    int row = id >> 4, c8 = id & 15;
    const float* kp = &qkv_lds[row * 388 + 128 + c8 * 8];
    const float* vp = &qkv_lds[row * 388 + 256 + c8 * 8];
    union { unsigned short us[8]; uint4 u4; } ko, vo;
#pragma unroll
    for (int j = 0; j < 8; ++j) { ko.us[j] = f2bf(kp[j]); vo.us[j] = f2bf(vp[j]); }
    *(uint4*)&KmBF[(b * Nn + n0 + row) * Cn + c8 * 8] = ko.u4;
    *(uint4*)&VmBF[(b * Nn + n0 + row) * Cn + c8 * 8] = vo.u4;
  }
}

// ---------------- K2: kvT[b,k,d,c] += sum_n Vrel[n,d]*Knorm[n,c]  (MFMA) ----------------
#define CH2 8
__global__ __launch_bounds__(256, 2) void k2_kv(const float* __restrict__ pos,
                                                const float* __restrict__ dist,
                                                const int* __restrict__ idxp,
                                                const float* __restrict__ W1,
                                                const float* __restrict__ b1,
                                                const float* __restrict__ b2,
                                                float* ws) {
  __shared__ __align__(16) unsigned short h_lds[32 * 72];  // [n][h]
  __shared__ float pe_lds[32 * 132];                        // [n][c]
  __shared__ __align__(16) unsigned short KnT[128 * 40];   // [c][n-swz]
  __shared__ __align__(16) unsigned short VrT[128 * 40];   // [d][n-swz]
  __shared__ float W1s[640];
  __shared__ float b1s[64];
  __shared__ float b2s[128];
  __shared__ int jn_s[32];

  const unsigned short* KmBF = (const unsigned short*)(ws + OFF_KMBF);
  const unsigned short* VmBF = (const unsigned short*)(ws + OFF_VMBF);
  const unsigned short* W2g = (const unsigned short*)(ws + OFF_W2BFG);
  float* kvt = ws + OFF_KVT32;
  int flag = ((const int*)(ws + OFF_FLAG))[0];

  // XCD-locality decode: b in low 2 bits -> batch b lands on XCDs {b, b+4}
  int bid = blockIdx.x;
  int b = bid & 3;
  int rest = bid >> 2;
  int k = rest & 15, ch = rest >> 4;
  int t = threadIdx.x;
  int w = t >> 6, l = t & 63;
  int ml = l & 15, gq = l >> 4;

  for (int i = t; i < 640; i += 256) W1s[i] = W1[i];
  if (t < 64) b1s[t] = b1[t];
  if (t < 128) b2s[t] = b2[t];

  f32x4 acc[2][8];
#pragma unroll
  for (int i = 0; i < 2; ++i)
#pragma unroll
    for (int j = 0; j < 8; ++j) acc[i][j] = (f32x4)0.f;

  int g = t >> 3, l8 = t & 7;      // phases A, B2

  for (int it = 0; it < 16; ++it) {
    int n0 = ch * 512 + it * 32;
    __syncthreads();
    // ---- Phase A: feat10 + MLP layer1 -> h_lds bf16 ----
    {
      int n = n0 + g;
      int fidx = (b * Nn + n) * Kn + k;
      int jn = flag ? idxp[2 * fidx] : idxp[fidx];
      if (l8 == 0) jn_s[g] = jn;
      float dd = dist[fidx];
      float pc0 = pos[(b * Nn + n) * 3 + 0], pc1 = pos[(b * Nn + n) * 3 + 1], pc2 = pos[(b * Nn + n) * 3 + 2];
      float pn0 = pos[(b * Nn + jn) * 3 + 0], pn1 = pos[(b * Nn + jn) * 3 + 1], pn2 = pos[(b * Nn + jn) * 3 + 2];
      float f10[10] = {pc0, pc1, pc2, pn0, pn1, pn2, pc0 - pn0, pc1 - pn1, pc2 - pn2, dd};
      union { unsigned short us[8]; uint4 u4; } hv;
#pragma unroll
      for (int oo = 0; oo < 8; ++oo) {
        int o = l8 * 8 + oo;
        float a = b1s[o];
#pragma unroll
        for (int i2 = 0; i2 < 10; ++i2) a = fmaf(W1s[o * 10 + i2], f10[i2], a);
        hv.us[oo] = f2bf(fmaxf(a, 0.f));
      }
      *(uint4*)&h_lds[g * 72 + l8 * 8] = hv.u4;
    }
    __syncthreads();
    // ---- Phase B1 (MFMA): pe[n][c] = h @ W2^T + b2 -> pe_lds f32 ----
    {
      f32x4 pacc[2][2];
#pragma unroll
      for (int i = 0; i < 2; ++i)
#pragma unroll
        for (int j = 0; j < 2; ++j) pacc[i][j] = (f32x4)0.f;
#pragma unroll
      for (int hc = 0; hc < 64; hc += 32) {
        bf16x8 av[2];
#pragma unroll
        for (int mf = 0; mf < 2; ++mf)
          av[mf] = *(const bf16x8*)&h_lds[(ml + 16 * mf) * 72 + hc + 8 * gq];
#pragma unroll
        for (int nf = 0; nf < 2; ++nf) {
          int c = 32 * w + 16 * nf + ml;
          bf16x8 bv = *(const bf16x8*)&W2g[c * 64 + hc + 8 * gq];
          pacc[0][nf] = __builtin_amdgcn_mfma_f32_16x16x32_bf16(av[0], bv, pacc[0][nf], 0, 0, 0);
          pacc[1][nf] = __builtin_amdgcn_mfma_f32_16x16x32_bf16(av[1], bv, pacc[1][nf], 0, 0, 0);
        }
      }
#pragma unroll
      for (int mf = 0; mf < 2; ++mf)
#pragma unroll
        for (int nf = 0; nf < 2; ++nf) {
          int c = 32 * w + 16 * nf + ml;
          float b2v = b2s[c];
#pragma unroll
          for (int r = 0; r < 4; ++r)
            pe_lds[(16 * mf + 4 * gq + r) * 132 + c] = pacc[mf][nf][r] + b2v;
        }
    }
    __syncthreads();
    // ---- Phase B2: gather K/V bf16 (vectorized), +pe, normalize, swizzled transposed stores ----
    {
      int jn = jn_s[g];
      const unsigned short* krow = &KmBF[(b * Nn + jn) * Cn];
      const unsigned short* vrow = &VmBF[(b * Nn + jn) * Cn];
      union { unsigned short us[8]; uint4 u4; } ka, kb, va, vb;
      ka.u4 = *(const uint4*)&krow[l8 * 16];
      kb.u4 = *(const uint4*)&krow[l8 * 16 + 8];
      va.u4 = *(const uint4*)&vrow[l8 * 16];
      vb.u4 = *(const uint4*)&vrow[l8 * 16 + 8];
      float kr[16], vr[16];
      float ss = 0.f;
#pragma unroll
      for (int q = 0; q < 4; ++q) {
        float4 p = *(const float4*)&pe_lds[g * 132 + l8 * 16 + 4 * q];
        float pv[4] = {p.x, p.y, p.z, p.w};
#pragma unroll
        for (int j2 = 0; j2 < 4; ++j2) {
          int j = 4 * q + j2;
          unsigned short ku = (j < 8) ? ka.us[j] : kb.us[j - 8];
          unsigned short vu = (j < 8) ? va.us[j] : vb.us[j - 8];
          kr[j] = b2f(ku) + pv[j2];
          vr[j] = fmaxf(b2f(vu) + pv[j2], 0.f);
          ss = fmaf(kr[j], kr[j], ss);
        }
      }
      ss += __shfl_xor(ss, 1); ss += __shfl_xor(ss, 2); ss += __shfl_xor(ss, 4);
      float sc = 1.f / fmaxf(sqrtf(ss), 1e-12f);
#pragma unroll
      for (int j = 0; j < 16; ++j) {
        int c = l8 * 16 + j;
        int sw = g ^ (((c >> 4) & 3) << 3);   // 16B-granule XOR swizzle
        KnT[c * 40 + sw] = f2bf(kr[j] * sc);
        VrT[c * 40 + sw] = f2bf(vr[j]);
      }
    }
    __syncthreads();
    // ---- Phase C (MFMA): kvT[d][c] += VrT[d][:] * KnT[c][:] ----
    {
      bf16x8 av[2];
#pragma unroll
      for (int mf = 0; mf < 2; ++mf) {
        int d = 32 * w + 16 * mf + ml;
        av[mf] = *(const bf16x8*)&VrT[d * 40 + (8 * gq ^ ((((d >> 4) & 3)) << 3))];
      }
#pragma unroll
      for (int nf = 0; nf < 8; ++nf) {
        int c = 16 * nf + ml;
        bf16x8 bv = *(const bf16x8*)&KnT[c * 40 + (8 * gq ^ ((((c >> 4) & 3)) << 3))];
#pragma unroll
        for (int mf = 0; mf < 2; ++mf)
          acc[mf][nf] = __builtin_amdgcn_mfma_f32_16x16x32_bf16(av[mf], bv, acc[mf][nf], 0, 0, 0);
      }
    }
  }
  float* kvp = kvt + (b * Kn + k) * Cn * Cn;
#pragma unroll
  for (int mf = 0; mf < 2; ++mf)
#pragma unroll
    for (int nf = 0; nf < 8; ++nf) {
      int c = 16 * nf + ml;
#pragma unroll
      for (int r = 0; r < 4; ++r) {
        int d = 32 * w + 16 * mf + 4 * gq + r;
        atomicAdd(&kvp[d * Cn + c], acc[mf][nf][r]);
      }
    }
}

// ---------------- K2b: kvT f32 -> bf16 ----------------
__global__ __launch_bounds__(256) void k2b_cvt(float* ws) {
  const float* src = ws + OFF_KVT32;
  unsigned short* dst = (unsigned short*)(ws + OFF_KVTBF);
  int i = blockIdx.x * 256 + threadIdx.x;
  float4 a = *(const float4*)&src[i * 8];
  float4 c = *(const float4*)&src[i * 8 + 4];
  union { unsigned short us[8]; uint4 u4; } o;
  o.us[0] = f2bf(a.x); o.us[1] = f2bf(a.y); o.us[2] = f2bf(a.z); o.us[3] = f2bf(a.w);
  o.us[4] = f2bf(c.x); o.us[5] = f2bf(c.y); o.us[6] = f2bf(c.z); o.us[7] = f2bf(c.w);
  *(uint4*)&dst[i * 8] = o.u4;
}

// ---------------- K3: agg partials via gathered MFMA GEMM ----------------
__global__ __launch_bounds__(256, 4) void k3_agg(const int* __restrict__ idxp, float* ws) {
  __shared__ __align__(16) unsigned short qt[32 * 136];  // [n][c]
  const unsigned short* Qnbf = (const unsigned short*)(ws + OFF_QNBF);
  const unsigned short* kvtbf = (const unsigned short*)(ws + OFF_KVTBF);
  int flag = ((const int*)(ws + OFF_FLAG))[0];

  // XCD-locality decode: b in low 2 bits
  int bid = blockIdx.x;
  int b = bid & 3;
  int kh = (bid >> 2) & 1;
  int nt = bid >> 3;
  int n0 = nt * 32;
  int t = threadIdx.x;
  int w = t >> 6, l = t & 63;
  int ml = l & 15, gq = l >> 4;

  f32x4 acc[2][2];
#pragma unroll
  for (int i = 0; i < 2; ++i)
#pragma unroll
    for (int j = 0; j < 2; ++j) acc[i][j] = (f32x4)0.f;

  for (int kk = 0; kk < 8; ++kk) {
    int k = kh * 8 + kk;
    __syncthreads();
#pragma unroll
    for (int i = 0; i < 2; ++i) {
      int id = t + 256 * i;
      int row = id >> 4, c16 = id & 15;
      int fidx = (b * Nn + n0 + row) * Kn + k;
      int jn = flag ? idxp[2 * fidx] : idxp[fidx];
      uint4 v = *(const uint4*)&Qnbf[(b * Nn + jn) * Cn + c16 * 8];
      *(uint4*)&qt[row * 136 + c16 * 8] = v;
    }
    __syncthreads();
    const unsigned short* kvp = &kvtbf[(b * Kn + k) * Cn * Cn];
#pragma unroll
    for (int c0 = 0; c0 < 128; c0 += 32) {
      bf16x8 a0 = *(const bf16x8*)&qt[ml * 136 + c0 + 8 * gq];
      bf16x8 a1 = *(const bf16x8*)&qt[(ml + 16) * 136 + c0 + 8 * gq];
#pragma unroll
      for (int nf = 0; nf < 2; ++nf) {
        int d = 32 * w + 16 * nf + ml;
        bf16x8 bv = *(const bf16x8*)&kvp[d * Cn + c0 + 8 * gq];
        acc[0][nf] = __builtin_amdgcn_mfma_f32_16x16x32_bf16(a0, bv, acc[0][nf], 0, 0, 0);
        acc[1][nf] = __builtin_amdgcn_mfma_f32_16x16x32_bf16(a1, bv, acc[1][nf], 0, 0, 0);
      }
    }
  }
  float* ag = ws + (kh ? OFF_AGG1 : OFF_AGG0);
#pragma unroll
  for (int mf = 0; mf < 2; ++mf)
#pragma unroll
    for (int nf = 0; nf < 2; ++nf) {
      int d = 32 * w + 16 * nf + ml;
#pragma unroll
      for (int r = 0; r < 4; ++r) {
        int n = n0 + 16 * mf + 4 * gq + r;
        ag[(b * Nn + n) * Cn + d] = acc[mf][nf][r];
      }
    }
}

// ---------------- K4: out = relu(agg@Wm1^T+bm1)@Wm2^T + bm2 + xt  (MFMA) ----------------
__global__ __launch_bounds__(256, 2) void k4_mlp(const float* __restrict__ x,
                                                 const float* __restrict__ bm1,
                                                 const float* __restrict__ bm2,
                                                 float* __restrict__ out, float* ws) {
  __shared__ __align__(16) unsigned short a_lds[32 * 136];  // [n][c] bf16
  __shared__ __align__(16) unsigned short h_lds[32 * 520];  // [n][h] bf16
  __shared__ float out_s[128 * 33];                          // [co][n]
  const float* agg0 = ws + OFF_AGG0;
  const float* agg1 = ws + OFF_AGG1;
  const unsigned short* Wm1bf = (const unsigned short*)(ws + OFF_WM1BF);
  const unsigned short* Wm2bf = (const unsigned short*)(ws + OFF_WM2BF);
  const float invN = 1.f / (float)Nn;
  int b = blockIdx.x >> 7;
  int n0 = (blockIdx.x & 127) << 5;
  int t = threadIdx.x;
  int w = t >> 6, l = t & 63, ml = l & 15, gq = l >> 4;
#pragma unroll
  for (int i = 0; i < 4; ++i) {
    int id = t + 256 * i;
    int row = id >> 5, c4 = id & 31;
    int off = (b * Nn + n0 + row) * Cn + c4 * 4;
    float4 v0 = *(const float4*)&agg0[off];
    float4 v1 = *(const float4*)&agg1[off];
    union { unsigned short us[4]; uint2 u2; } o;
    o.us[0] = f2bf((v0.x + v1.x) * invN); o.us[1] = f2bf((v0.y + v1.y) * invN);
    o.us[2] = f2bf((v0.z + v1.z) * invN); o.us[3] = f2bf((v0.w + v1.w) * invN);
    *(uint2*)&a_lds[row * 136 + c4 * 4] = o.u2;
  }
  __syncthreads();
  // layer1: wave w -> h cols [128w, 128w+128)
  {
    f32x4 hacc[2][8];
#pragma unroll
    for (int i = 0; i < 2; ++i)
#pragma unroll
      for (int j = 0; j < 8; ++j) hacc[i][j] = (f32x4)0.f;
#pragma unroll
    for (int kc = 0; kc < 4; ++kc) {
      bf16x8 av0 = *(const bf16x8*)&a_lds[ml * 136 + kc * 32 + 8 * gq];
      bf16x8 av1 = *(const bf16x8*)&a_lds[(ml + 16) * 136 + kc * 32 + 8 * gq];
#pragma unroll
      for (int nf = 0; nf < 8; ++nf) {
        int h = 128 * w + 16 * nf + ml;
        bf16x8 bv = *(const bf16x8*)&Wm1bf[h * 128 + kc * 32 + 8 * gq];
        hacc[0][nf] = __builtin_amdgcn_mfma_f32_16x16x32_bf16(av0, bv, hacc[0][nf], 0, 0, 0);
        hacc[1][nf] = __builtin_amdgcn_mfma_f32_16x16x32_bf16(av1, bv, hacc[1][nf], 0, 0, 0);
      }
    }
#pragma unroll
    for (int mf = 0; mf < 2; ++mf)
#pragma unroll
      for (int nf = 0; nf < 8; ++nf) {
        int h = 128 * w + 16 * nf + ml;
        float bias = bm1[h];
#pragma unroll
        for (int r = 0; r < 4; ++r)
          h_lds[(16 * mf + 4 * gq + r) * 520 + h] = f2bf(fmaxf(hacc[mf][nf][r] + bias, 0.f));
      }
  }
  __syncthreads();
  // layer2: wave w -> co cols [32w, 32w+32)
  {
    f32x4 oacc[2][2];
#pragma unroll
    for (int i = 0; i < 2; ++i)
#pragma unroll
      for (int j = 0; j < 2; ++j) oacc[i][j] = (f32x4)0.f;
#pragma unroll
    for (int kc = 0; kc < 16; ++kc) {
      bf16x8 av0 = *(const bf16x8*)&h_lds[ml * 520 + kc * 32 + 8 * gq];
      bf16x8 av1 = *(const bf16x8*)&h_lds[(ml + 16) * 520 + kc * 32 + 8 * gq];
#pragma unroll
      for (int nf = 0; nf < 2; ++nf) {
        int co = 32 * w + 16 * nf + ml;
        bf16x8 bv = *(const bf16x8*)&Wm2bf[co * 512 + kc * 32 + 8 * gq];
        oacc[0][nf] = __builtin_amdgcn_mfma_f32_16x16x32_bf16(av0, bv, oacc[0][nf], 0, 0, 0);
        oacc[1][nf] = __builtin_amdgcn_mfma_f32_16x16x32_bf16(av1, bv, oacc[1][nf], 0, 0, 0);
      }
    }
#pragma unroll
    for (int mf = 0; mf < 2; ++mf)
#pragma unroll
      for (int nf = 0; nf < 2; ++nf) {
        int co = 32 * w + 16 * nf + ml;
        float bias = bm2[co];
#pragma unroll
        for (int r = 0; r < 4; ++r)
          out_s[co * 33 + 16 * mf + 4 * gq + r] = oacc[mf][nf][r] + bias;
      }
  }
  __syncthreads();
#pragma unroll
  for (int i = 0; i < 16; ++i) {
    int id = t + 256 * i;
    int co = id >> 5, j = id & 31;
    out[(b * Cn + co) * Nn + n0 + j] = out_s[co * 33 + j] + x[(b * Cn + co) * Nn + n0 + j];
  }
}

extern "C" void kernel_launch(void* const* d_in, const int* in_sizes, int n_in,
                              void* d_out, int out_size, void* d_ws, size_t ws_size,
                              hipStream_t stream) {
  const float* pos  = (const float*)d_in[0];
  const float* x    = (const float*)d_in[1];
  const int*   idx  = (const int*)d_in[2];
  const float* dist = (const float*)d_in[3];
  const float* Wqkv = (const float*)d_in[4];
  const float* W1   = (const float*)d_in[5];
  const float* b1   = (const float*)d_in[6];
  const float* W2   = (const float*)d_in[7];
  const float* b2   = (const float*)d_in[8];
  const float* Wm1  = (const float*)d_in[9];
  const float* bm1  = (const float*)d_in[10];
  const float* Wm2  = (const float*)d_in[11];
  const float* bm2  = (const float*)d_in[12];
  float* out = (float*)d_out;
  float* ws = (float*)d_ws;

  hipMemsetAsync(ws + OFF_KVT32, 0, (size_t)Bn * Kn * Cn * Cn * sizeof(float), stream);
  hipLaunchKernelGGL(k0_prep, dim3(736), dim3(256), 0, stream, Wqkv, Wm1, Wm2, W2, idx, ws);
  hipLaunchKernelGGL(k1_qkv, dim3(Bn * 128), dim3(256), 0, stream, x, ws);
  hipLaunchKernelGGL(k2_kv, dim3(Bn * Kn * CH2), dim3(256), 0, stream, pos, dist, idx, W1, b1, b2, ws);
  hipLaunchKernelGGL(k2b_cvt, dim3(512), dim3(256), 0, stream, ws);
  hipLaunchKernelGGL(k3_agg, dim3(Bn * 2 * 128), dim3(256), 0, stream, idx, ws);
  hipLaunchKernelGGL(k4_mlp, dim3(Bn * 128), dim3(256), 0, stream, x, bm1, bm2, out, ws);
}